// Round 10
// baseline (1404.327 us; speedup 1.0000x reference)
//
#include <hip/hip_runtime.h>
#include <hip/hip_bf16.h>
#include <hip/hip_fp16.h>
#include <cstddef>

// MCSHeteroGNN: 2-layer hetero GAT, CSR-gather, precomputed f16 edge weights,
// lane=(edge-slot, channel-octet) gather kernel.
// Node types: idle(100k), quasi(100k), task(50k). 5 edge types x 500k edges.
//
// ws layout (bytes):
//   flag    @ 0
//   params  @ 256          (~345 KB tight-packed f32 params, inputs 3..15)
//   h  bf16 @ 400,000      (32,000,000) [idle|quasi|task]
//   hs bf16 @ 32,400,000   (57,600,000) [450k x 64, by src-side etype]
//   als f32 @ 90,000,000   ( 7,200,000) [450k x 4]
//   rowptr  @ 97,200,000   (5 x 400,032)
//   cursor  @ 99,200,256   (5 x 400,032)
//   cols    @ 101,200,640  (5 x 2,000,000)
//   part    @ 111,200,640  (5 x 2,048)
//   ald f32 @ 121,211,008  ( 7,200,000) [450k x 4, packed dst-side]
//   wbuf f16@ 128,411,008  ( 8,000,064) [2 slots x 500k x 4]

static constexpr int NI = 100000, NQ = 100000, NT = 50000, NE = 500000;

__device__ __forceinline__ float b2f(__hip_bfloat16 x) { return __bfloat162float(x); }
__device__ __forceinline__ __hip_bfloat16 f2b(float x) { return __float2bfloat16(x); }
__device__ __forceinline__ unsigned short bbits(float x)
{
    __hip_bfloat16 b = f2b(x);
    unsigned short u;
    __builtin_memcpy(&u, &b, 2);
    return u;
}
__device__ __forceinline__ void bf16x8_to_f32(uint4 r, float* f)
{
    unsigned v[4] = { r.x, r.y, r.z, r.w };
#pragma unroll
    for (int i = 0; i < 4; ++i) {
        f[2 * i]     = __int_as_float((int)(v[i] << 16));
        f[2 * i + 1] = __int_as_float((int)(v[i] & 0xffff0000u));
    }
}

__global__ void k_detect(const unsigned short* __restrict__ x, int* __restrict__ flag)
{
    __shared__ int sh[256];
    int tid = threadIdx.x;
    int sane = 0;
    for (int i = tid * 2; i < 2048; i += 512) {
        unsigned short h = x[i];
        int e = (h >> 7) & 0xFF;
        if (h == 0 || (e >= 100 && e <= 140)) sane++;
    }
    sh[tid] = sane;
    __syncthreads();
    for (int s = 128; s; s >>= 1) { if (tid < s) sh[tid] += sh[tid + s]; __syncthreads(); }
    if (tid == 0) *flag = (sh[0] < 512) ? 1 : 0;   // 1 = buffers are f32
}

struct ConvArgs { const void* src[16]; float* dst[16]; int n[16]; };

__global__ void k_convert(ConvArgs a, const int* __restrict__ flag)
{
    int t = blockIdx.y;
    int i = blockIdx.x * 256 + threadIdx.x;
    if (i >= a.n[t]) return;
    float v = (*flag) ? ((const float*)a.src[t])[i]
                      : b2f(((const __hip_bfloat16*)a.src[t])[i]);
    a.dst[t][i] = v;
}

// ------------- input projection: h = relu(x @ W + b), dual-dtype -----------
__global__ void k_inproj(const void* __restrict__ xv, int N, int F,
                         const float* __restrict__ W, const float* __restrict__ b,
                         __hip_bfloat16* __restrict__ h, const int* __restrict__ flag)
{
    __shared__ float Wsh[8 * 64];
    __shared__ float bsh[64];
    int tid = threadIdx.x;
    for (int i = tid; i < F * 64; i += 256) Wsh[i] = W[i];
    if (tid < 64) bsh[tid] = b[tid];
    __syncthreads();
    int col = tid & 63;
    int n = blockIdx.x * 4 + (tid >> 6);
    if (n >= N) return;
    float acc = bsh[col];
    if (*flag) {
        const float* xr = (const float*)xv + (size_t)n * F;
        for (int k = 0; k < F; ++k) acc += xr[k] * Wsh[k * 64 + col];
    } else {
        const __hip_bfloat16* xr = (const __hip_bfloat16*)xv + (size_t)n * F;
        for (int k = 0; k < F; ++k) acc += b2f(xr[k]) * Wsh[k * 64 + col];
    }
    h[(size_t)n * 64 + col] = f2b(fmaxf(acc, 0.f));
}

// ---- all 5 etypes' hs = h_src @ Wsrc + als; W in VGPRs, h via readlane ----
struct TfArgs {
    const __hip_bfloat16* hsrc[5];
    const float* W[5];
    const float* avec[5];
    __hip_bfloat16* hs[5];
    float* als[5];
};
__global__ void __launch_bounds__(256) k_transform_all(TfArgs a)
{
    int tid = threadIdx.x;
    int c = tid & 63, wid = tid >> 6;
    int base = blockIdx.x * 80;               // 80 rows/block; boundaries at x100k
    int j = base / 100000;
    const float* W = a.W[j];
    float wreg[64];
#pragma unroll
    for (int k = 0; k < 64; ++k) wreg[k] = W[k * 64 + c];
    float ac = a.avec[j][c];
    int nl0 = base - j * 100000 + wid * 20;
    const __hip_bfloat16* hsrc = a.hsrc[j];
    __hip_bfloat16* hs = a.hs[j];
    float* als = a.als[j];
    for (int r = 0; r < 20; ++r) {
        int nl = nl0 + r;
        float hv = b2f(hsrc[(size_t)nl * 64 + c]);
        int hb = __float_as_int(hv);
        float a0 = 0.f, a1 = 0.f, a2 = 0.f, a3 = 0.f;
#pragma unroll
        for (int k = 0; k < 64; k += 4) {
            float h0 = __int_as_float(__builtin_amdgcn_readlane(hb, k));
            float h1 = __int_as_float(__builtin_amdgcn_readlane(hb, k + 1));
            float h2 = __int_as_float(__builtin_amdgcn_readlane(hb, k + 2));
            float h3 = __int_as_float(__builtin_amdgcn_readlane(hb, k + 3));
            a0 = fmaf(h0, wreg[k], a0);
            a1 = fmaf(h1, wreg[k + 1], a1);
            a2 = fmaf(h2, wreg[k + 2], a2);
            a3 = fmaf(h3, wreg[k + 3], a3);
        }
        float acc = (a0 + a1) + (a2 + a3);
        hs[(size_t)nl * 64 + c] = f2b(acc);
        float p = acc * ac;
        p += __shfl_xor(p, 8, 16);
        p += __shfl_xor(p, 4, 16);
        p += __shfl_xor(p, 2, 16);
        p += __shfl_xor(p, 1, 16);
        if ((c & 15) == 0) als[(size_t)nl * 4 + (c >> 4)] = p;
    }
}

// ------ ald for all 5 dst-sides: ald[n][h] = <h_dst[n], Weff_h> ------------
struct AldArgs {
    const __hip_bfloat16* hdst[5];
    const float* Wd[5];
    const float* ad[5];
    float* ald;          // packed: bases {0,100k,200k,300k,350k}
};
__global__ void k_ald_all(AldArgs a)
{
    __shared__ float We[256];
    int tid = threadIdx.x;
    int base = blockIdx.x * 80;               // packed ald index space (450k)
    int j = (base < 100000) ? 0 : (base < 200000) ? 1 : (base < 300000) ? 2
          : (base < 350000) ? 3 : 4;
    const int startj[5] = { 0, 100000, 200000, 300000, 350000 };
    {
        int k = tid >> 2, h2 = tid & 3;
        const float* Wd = a.Wd[j];
        const float* ad = a.ad[j];
        float s = 0.f;
        for (int cc = 0; cc < 16; ++cc)
            s += Wd[k * 64 + h2 * 16 + cc] * ad[h2 * 16 + cc];
        We[tid] = s;
    }
    __syncthreads();
    int c = tid & 63, wid = tid >> 6;
    int nl0 = base - startj[j] + wid * 20;
    const __hip_bfloat16* hd = a.hdst[j];
    for (int r = 0; r < 20; ++r) {
        int nl = nl0 + r;
        float hv = b2f(hd[(size_t)nl * 64 + c]);
#pragma unroll
        for (int hp = 0; hp < 4; ++hp) {
            float v = hv * We[c * 4 + hp];
            v += __shfl_xor(v, 32, 64);
            v += __shfl_xor(v, 16, 64);
            v += __shfl_xor(v, 8, 64);
            v += __shfl_xor(v, 4, 64);
            v += __shfl_xor(v, 2, 64);
            v += __shfl_xor(v, 1, 64);
            if (c == hp) a.ald[(size_t)(startj[j] + nl) * 4 + hp] = v;
        }
    }
}

// ------------------- batched counting sort by dst (5 etypes) ---------------
struct SortArgs {
    const int* ei[5]; int* rowptr[5]; int* cursor[5]; int* cols[5]; int* part[5];
    int n[5];   // Ndst+1
};
__global__ void k_hist5(SortArgs s)
{
    int j = blockIdx.y;
    int e = blockIdx.x * 256 + threadIdx.x;
    if (e >= NE) return;
    atomicAdd(&s.rowptr[j][s.ei[j][NE + e] + 1], 1);
}
__global__ void k_scanb5(SortArgs s)
{
    __shared__ int sh[256];
    int j = blockIdx.y;
    int* a = s.rowptr[j];
    int n = s.n[j];
    int tid = threadIdx.x;
    int i = blockIdx.x * 256 + tid;
    int v = (i < n) ? a[i] : 0;
    sh[tid] = v; __syncthreads();
    for (int off = 1; off < 256; off <<= 1) {
        int t = (tid >= off) ? sh[tid - off] : 0;
        __syncthreads();
        sh[tid] += t;
        __syncthreads();
    }
    if (i < n) a[i] = sh[tid];
    if (tid == 255) s.part[j][blockIdx.x] = sh[255];
}
__global__ void k_scanp5(SortArgs s)
{
    __shared__ int sh[512];
    int j = blockIdx.x;
    int* part = s.part[j];
    int tid = threadIdx.x;
    int v = (tid < 391) ? part[tid] : 0;
    sh[tid] = v; __syncthreads();
    for (int off = 1; off < 512; off <<= 1) {
        int t = (tid >= off) ? sh[tid - off] : 0;
        __syncthreads();
        sh[tid] += t;
        __syncthreads();
    }
    if (tid < 391) part[tid] = sh[tid] - v;    // exclusive
}
__global__ void k_scana5(SortArgs s)
{
    int j = blockIdx.y;
    int i = blockIdx.x * 256 + threadIdx.x;
    if (i < s.n[j]) s.rowptr[j][i] += s.part[j][blockIdx.x];
}
__global__ void k_scatter5(SortArgs s)
{
    int j = blockIdx.y;
    int e = blockIdx.x * 256 + threadIdx.x;
    if (e >= NE) return;
    const int* ei = s.ei[j];
    int src = ei[e], d = ei[NE + e];
    int pos = atomicAdd(&s.cursor[j][d], 1);
    s.cols[j][pos] = src;
}

// --- node-parallel edge weights: w[e][hh] = exp(min(leaky(als+ald),11)) ----
struct WedgeArgs {
    const int* rp[2]; const int* cols[2];
    const float* als[2]; const float* ald[2];
    __half* wout[2]; int N;
};
__global__ void k_wedge(WedgeArgs a)
{
    int sl = blockIdx.y;
    int gid = blockIdx.x * 256 + threadIdx.x;
    int n = gid >> 2, hh = gid & 3;
    if (n >= a.N) return;
    float aldv = a.ald[sl][(size_t)n * 4 + hh];
    const int* cols = a.cols[sl];
    const float* als = a.als[sl];
    __half* w = a.wout[sl];
    int beg = a.rp[sl][n], end = a.rp[sl][n + 1];
    for (int e = beg; e < end; ++e) {
        int src = cols[e];
        float al = als[(size_t)src * 4 + hh] + aldv;
        al = (al > 0.f) ? al : 0.2f * al;      // leaky_relu 0.2
        w[(size_t)e * 4 + hh] = __float2half(__expf(fminf(al, 11.f)));
    }
}

// ---- per-dst gather: lane = (edge-slot u, channel-octet o) ----------------
__device__ __forceinline__ void addside(int n, int u, int o, int hh,
    const int* __restrict__ rp, const int* __restrict__ cols,
    const __hip_bfloat16* __restrict__ hs, const __half* __restrict__ wb,
    float x[8])
{
    float acc[8] = { 0.f, 0.f, 0.f, 0.f, 0.f, 0.f, 0.f, 0.f };
    float den = 0.f;
    int beg = rp[n], end = rp[n + 1];
    for (int e0 = beg; e0 < end; e0 += 8) {
        int e = e0 + u;
        bool valid = e < end;
        int ec = valid ? e : end - 1;
        int src = cols[ec];
        float wv = __half2float(wb[(size_t)ec * 4 + hh]);
        wv = valid ? wv : 0.f;
        uint4 hraw = *(const uint4*)(hs + (size_t)src * 64 + o * 8);
        float hv[8];
        bf16x8_to_f32(hraw, hv);
#pragma unroll
        for (int j = 0; j < 8; ++j) acc[j] = fmaf(wv, hv[j], acc[j]);
        den += wv;
    }
    // butterfly over edge-slot bits {8,16,32}
#pragma unroll
    for (int m = 8; m <= 32; m <<= 1) {
#pragma unroll
        for (int j = 0; j < 8; ++j) acc[j] += __shfl_xor(acc[j], m, 64);
        den += __shfl_xor(den, m, 64);
    }
    float inv = 1.f / (den + 1e-16f);
#pragma unroll
    for (int j = 0; j < 8; ++j) x[j] += acc[j] * inv;
}

struct DstArgs {
    __hip_bfloat16* h; int net; int last; int pad;
    const int* rp0; const int* cols0; const __hip_bfloat16* hs0; const __half* w0;
    const int* rp1; const int* cols1; const __hip_bfloat16* hs1; const __half* w1;
    const float* b0; const float* b1;
    const float* g; const float* bb;
    void* out; size_t obase; const int* flag;
};
__global__ void __launch_bounds__(256) k_dst(DstArgs a)
{
    int tid = threadIdx.x;
    int lane = tid & 63, wid = tid >> 6;
    int u = lane >> 3;        // edge slot 0..7
    int o = lane & 7;         // channel octet: channels o*8 .. o*8+7
    int hh = o >> 1;          // head for these channels
    float b01v[8], gv[8], bbv[8];
#pragma unroll
    for (int j = 0; j < 8; ++j) {
        int c = o * 8 + j;
        b01v[j] = a.b0[c] + ((a.net > 1) ? a.b1[c] : 0.f);
        gv[j] = a.g[c];
        bbv[j] = a.bb[c];
    }
    int base = blockIdx.x * 16;               // 16 nodes/block; N multiple of 16
    for (int r = 0; r < 4; ++r) {
        int n = base + r * 4 + wid;
        uint4 hraw = *(const uint4*)(a.h + (size_t)n * 64 + o * 8);
        float x[8];
        bf16x8_to_f32(hraw, x);
#pragma unroll
        for (int j = 0; j < 8; ++j) x[j] += b01v[j];
        addside(n, u, o, hh, a.rp0, a.cols0, a.hs0, a.w0, x);
        if (a.net > 1) addside(n, u, o, hh, a.rp1, a.cols1, a.hs1, a.w1, x);
        // LayerNorm over 64 channels (x identical across u-lanes; reduce over o)
        float s = 0.f;
#pragma unroll
        for (int j = 0; j < 8; ++j) s += x[j];
        s += __shfl_xor(s, 1, 64);
        s += __shfl_xor(s, 2, 64);
        s += __shfl_xor(s, 4, 64);
        float mu = s * (1.f / 64.f);
        float v2 = 0.f;
#pragma unroll
        for (int j = 0; j < 8; ++j) { float d = x[j] - mu; v2 += d * d; }
        v2 += __shfl_xor(v2, 1, 64);
        v2 += __shfl_xor(v2, 2, 64);
        v2 += __shfl_xor(v2, 4, 64);
        float scale = rsqrtf(v2 * (1.f / 64.f) + 1e-5f);
        float y[8];
#pragma unroll
        for (int j = 0; j < 8; ++j)
            y[j] = fmaxf((x[j] - mu) * scale * gv[j] + bbv[j], 0.f);
        if (u == 0) {
            if (!a.last) {
                uint4 pk;
                unsigned* p = (unsigned*)&pk;
#pragma unroll
                for (int i = 0; i < 4; ++i)
                    p[i] = (unsigned)bbits(y[2 * i]) | ((unsigned)bbits(y[2 * i + 1]) << 16);
                *(uint4*)(a.h + (size_t)n * 64 + o * 8) = pk;
            } else if (*a.flag) {
                float* op = (float*)a.out + a.obase + (size_t)n * 64 + o * 8;
                float4 f0 = { y[0], y[1], y[2], y[3] };
                float4 f1 = { y[4], y[5], y[6], y[7] };
                *(float4*)op = f0;
                *(float4*)(op + 4) = f1;
            } else {
                uint4 pk;
                unsigned* p = (unsigned*)&pk;
#pragma unroll
                for (int i = 0; i < 4; ++i)
                    p[i] = (unsigned)bbits(y[2 * i]) | ((unsigned)bbits(y[2 * i + 1]) << 16);
                *(uint4*)((__hip_bfloat16*)a.out + a.obase + (size_t)n * 64 + o * 8) = pk;
            }
        }
    }
}

extern "C" void kernel_launch(void* const* d_in, const int* in_sizes, int n_in,
                              void* d_out, int out_size, void* d_ws, size_t ws_size,
                              hipStream_t stream)
{
    (void)n_in; (void)out_size; (void)ws_size;
    char* ws = (char*)d_ws;
    int* flag = (int*)ws;
    float* params = (float*)(ws + 256);

    // tight param offsets: only inputs 3..15 are widened
    size_t offp[16]; size_t cur = 0;
    for (int i = 3; i < 16; ++i) { offp[i] = cur; cur += (size_t)in_sizes[i]; }

    const float* Wi = params + offp[3]; const float* bi = params + offp[4];
    const float* Wq = params + offp[5]; const float* bq = params + offp[6];
    const float* Wt = params + offp[7]; const float* bt = params + offp[8];
    const float* Wsrc = params + offp[9];
    const float* Wdst = params + offp[10];
    const float* asrc = params + offp[11];
    const float* adst = params + offp[12];
    const float* cbias = params + offp[13];
    const float* lng = params + offp[14];
    const float* lnb = params + offp[15];

    __hip_bfloat16* h   = (__hip_bfloat16*)(ws + 400000);
    __hip_bfloat16* h_i = h;
    __hip_bfloat16* h_q = h + (size_t)NI * 64;
    __hip_bfloat16* h_t = h + (size_t)(NI + NQ) * 64;
    __hip_bfloat16* hs_all = (__hip_bfloat16*)(ws + 32400000);
    float* als_all = (float*)(ws + 90000000);
    float* ald_all = (float*)(ws + 121211008);
    __half* wbuf = (__half*)(ws + 128411008);
    const size_t rowbase[5] = { 0, 100000, 200000, 300000, 400000 };  // src-side
    const size_t aldbase[5] = { 0, 100000, 200000, 300000, 350000 };  // dst-side

    const size_t RPS = 400032;
    SortArgs sa;
    const int Ndst_of[5] = { NI, NQ, NI, NT, NQ };
    for (int j = 0; j < 5; ++j) {
        sa.ei[j]     = (const int*)d_in[16 + j];
        sa.rowptr[j] = (int*)(ws + 97200000 + j * RPS);
        sa.cursor[j] = (int*)(ws + 99200256 + j * RPS);
        sa.cols[j]   = (int*)(ws + 101200640 + (size_t)j * 2000000);
        sa.part[j]   = (int*)(ws + 111200640 + j * 2048);
        sa.n[j]      = Ndst_of[j] + 1;
    }

    // ---- dtype detect + widen PARAM tensors (3..15) only ----
    k_detect<<<1, 256, 0, stream>>>((const unsigned short*)d_in[0], flag);
    ConvArgs ca;
    for (int i = 0; i < 16; ++i) {
        ca.src[i] = d_in[i];
        ca.dst[i] = (i >= 3) ? (params + offp[i]) : nullptr;
        ca.n[i] = (i >= 3) ? in_sizes[i] : 0;
    }
    k_convert<<<dim3(160, 16), 256, 0, stream>>>(ca, flag);

    // ---- input projections ----
    k_inproj<<<(NI + 3) / 4, 256, 0, stream>>>(d_in[0], NI, 8, Wi, bi, h_i, flag);
    k_inproj<<<(NQ + 3) / 4, 256, 0, stream>>>(d_in[1], NQ, 6, Wq, bq, h_q, flag);
    k_inproj<<<(NT + 3) / 4, 256, 0, stream>>>(d_in[2], NT, 8, Wt, bt, h_t, flag);

    // ---- batched counting sort (reused by both layers) ----
    hipMemsetAsync(ws + 97200000, 0, 5 * RPS, stream);
    k_hist5<<<dim3((NE + 255) / 256, 5), 256, 0, stream>>>(sa);
    k_scanb5<<<dim3(391, 5), 256, 0, stream>>>(sa);
    k_scanp5<<<5, 512, 0, stream>>>(sa);
    k_scana5<<<dim3(391, 5), 256, 0, stream>>>(sa);
    hipMemcpyAsync(ws + 99200256, ws + 97200000, 5 * RPS, hipMemcpyDeviceToDevice, stream);
    k_scatter5<<<dim3((NE + 255) / 256, 5), 256, 0, stream>>>(sa);

    const __hip_bfloat16* hsrc_of[5] = { h_i, h_i, h_q, h_q, h_t };
    __hip_bfloat16* hdst_of[5] = { h_i, h_q, h_i, h_t, h_q };

    for (int l = 0; l < 2; ++l) {
        // hs/als for all 5 etypes (reads pre-update h)
        TfArgs ta;
        for (int j = 0; j < 5; ++j) {
            ta.hsrc[j] = hsrc_of[j];
            ta.W[j] = Wsrc + (size_t)(l * 5 + j) * 4096;
            ta.avec[j] = asrc + (l * 5 + j) * 64;
            ta.hs[j] = hs_all + rowbase[j] * 64;
            ta.als[j] = als_all + rowbase[j] * 4;
        }
        k_transform_all<<<5625, 256, 0, stream>>>(ta);

        // ald for all 5 dst-sides (reads pre-update h)
        AldArgs aa;
        for (int j = 0; j < 5; ++j) {
            aa.hdst[j] = hdst_of[j];
            aa.Wd[j] = Wdst + (size_t)(l * 5 + j) * 4096;
            aa.ad[j] = adst + (l * 5 + j) * 64;
        }
        aa.ald = ald_all;
        k_ald_all<<<5625, 256, 0, stream>>>(aa);

        int last = (l == 1);
        struct Spec { __hip_bfloat16* hd; int N; int j0, j1, lnidx; size_t obase; };
        Spec sp[3] = {
            { h_i, NI, 0, 2, 0, 0 },
            { h_q, NQ, 1, 4, 1, (size_t)NI * 64 },
            { h_t, NT, 3, -1, 2, (size_t)(NI + NQ) * 64 },
        };
        for (int t = 0; t < 3; ++t) {
            int net = (sp[t].j1 >= 0) ? 2 : 1;
            WedgeArgs wa;
            wa.N = sp[t].N;
            for (int s = 0; s < net; ++s) {
                int j = (s == 0) ? sp[t].j0 : sp[t].j1;
                wa.rp[s] = sa.rowptr[j];
                wa.cols[s] = sa.cols[j];
                wa.als[s] = als_all + rowbase[j] * 4;
                wa.ald[s] = ald_all + aldbase[j] * 4;
                wa.wout[s] = wbuf + (size_t)s * NE * 4;
            }
            if (net == 1) {
                wa.rp[1] = wa.rp[0]; wa.cols[1] = wa.cols[0];
                wa.als[1] = wa.als[0]; wa.ald[1] = wa.ald[0];
                wa.wout[1] = wa.wout[0];
            }
            k_wedge<<<dim3((sp[t].N * 4 + 255) / 256, net), 256, 0, stream>>>(wa);

            DstArgs dd;
            dd.h = sp[t].hd; dd.net = net; dd.last = last; dd.pad = 0;
            int j0 = sp[t].j0;
            dd.rp0 = sa.rowptr[j0]; dd.cols0 = sa.cols[j0];
            dd.hs0 = hs_all + rowbase[j0] * 64; dd.w0 = wbuf;
            int jj = (sp[t].j1 >= 0) ? sp[t].j1 : j0;
            dd.rp1 = sa.rowptr[jj]; dd.cols1 = sa.cols[jj];
            dd.hs1 = hs_all + rowbase[jj] * 64; dd.w1 = wbuf + (size_t)NE * 4;
            dd.b0 = cbias + (size_t)(l * 5 + j0) * 64;
            dd.b1 = cbias + (size_t)(l * 5 + jj) * 64;
            dd.g = lng + (size_t)(l * 3 + sp[t].lnidx) * 64;
            dd.bb = lnb + (size_t)(l * 3 + sp[t].lnidx) * 64;
            dd.out = d_out; dd.obase = sp[t].obase; dd.flag = flag;
            k_dst<<<sp[t].N / 16, 256, 0, stream>>>(dd);
        }
    }
}

// Round 11
// 1009.965 us; speedup vs baseline: 1.3905x; 1.3905x over previous
//
#include <hip/hip_runtime.h>
#include <hip/hip_bf16.h>
#include <cstddef>

// MCSHeteroGNN: 2-layer hetero GAT, CSR-gather, register-resident transforms,
// merged 3-type dst kernel with shfl-dedup'd attention weights.
// Node types: idle(100k), quasi(100k), task(50k). 5 edge types x 500k edges.
//
// ws layout (bytes), total ~118.5 MB:
//   flag    @ 0
//   params  @ 256         (f32 widened params; feature slots unused)
//   h  bf16 @ 7,600,000   (32,000,000) [idle|quasi|task]
//   hs bf16 @ 39,600,000  (57,600,000) [450k x 64]
//   als f32 @ 97,200,000  ( 7,200,000) [450k x 4]
//   rowptr  @104,400,000  (5 x 400,032)
//   cursor  @106,400,320  (5 x 400,032)
//   cols    @108,400,480  (5 x 2,000,000)
//   part    @118,400,480  (5 x 2,048)

static constexpr int NI = 100000, NQ = 100000, NT = 50000, NE = 500000;

__device__ __forceinline__ float b2f(__hip_bfloat16 x) { return __bfloat162float(x); }
__device__ __forceinline__ __hip_bfloat16 f2b(float x) { return __float2bfloat16(x); }

__global__ void k_detect(const unsigned short* __restrict__ x, int* __restrict__ flag)
{
    __shared__ int sh[256];
    int tid = threadIdx.x;
    int sane = 0;
    for (int i = tid * 2; i < 2048; i += 512) {
        unsigned short h = x[i];
        int e = (h >> 7) & 0xFF;
        if (h == 0 || (e >= 100 && e <= 140)) sane++;
    }
    sh[tid] = sane;
    __syncthreads();
    for (int s = 128; s; s >>= 1) { if (tid < s) sh[tid] += sh[tid + s]; __syncthreads(); }
    if (tid == 0) *flag = (sh[0] < 512) ? 1 : 0;   // 1 = buffers are f32
}

struct ConvArgs { const void* src[16]; float* dst[16]; int n[16]; };

__global__ void k_convert(ConvArgs a, const int* __restrict__ flag)
{
    int t = blockIdx.y;
    int i = blockIdx.x * 256 + threadIdx.x;
    if (i >= a.n[t]) return;
    float v = (*flag) ? ((const float*)a.src[t])[i]
                      : b2f(((const __hip_bfloat16*)a.src[t])[i]);
    a.dst[t][i] = v;
}

// ------------- input projection: h = relu(x @ W + b), dual-dtype -----------
__global__ void k_inproj(const void* __restrict__ xv, int N, int F,
                         const float* __restrict__ W, const float* __restrict__ b,
                         __hip_bfloat16* __restrict__ h, const int* __restrict__ flag)
{
    __shared__ float Wsh[8 * 64];
    __shared__ float bsh[64];
    int tid = threadIdx.x;
    for (int i = tid; i < F * 64; i += 256) Wsh[i] = W[i];
    if (tid < 64) bsh[tid] = b[tid];
    __syncthreads();
    int col = tid & 63;
    int n = blockIdx.x * 4 + (tid >> 6);
    if (n >= N) return;
    float acc = bsh[col];
    if (*flag) {
        const float* xr = (const float*)xv + (size_t)n * F;
        for (int k = 0; k < F; ++k) acc += xr[k] * Wsh[k * 64 + col];
    } else {
        const __hip_bfloat16* xr = (const __hip_bfloat16*)xv + (size_t)n * F;
        for (int k = 0; k < F; ++k) acc += b2f(xr[k]) * Wsh[k * 64 + col];
    }
    h[(size_t)n * 64 + col] = f2b(fmaxf(acc, 0.f));
}

// ---- all 5 etypes' hs = h_src @ Wsrc + als; W in VGPRs, h via readlane ----
struct TfArgs {
    const __hip_bfloat16* hsrc[5];
    const float* W[5];
    const float* avec[5];
    __hip_bfloat16* hs[5];
    float* als[5];
};
__global__ void __launch_bounds__(256) k_transform_all(TfArgs a)
{
    int tid = threadIdx.x;
    int c = tid & 63, wid = tid >> 6;
    int base = blockIdx.x * 80;               // 80 rows/block; 80 | 100000
    int j = base / 100000;
    const float* W = a.W[j];
    float wreg[64];
#pragma unroll
    for (int k = 0; k < 64; ++k) wreg[k] = W[k * 64 + c];
    float ac = a.avec[j][c];
    int nl0 = base - j * 100000 + wid * 20;
    const __hip_bfloat16* hsrc = a.hsrc[j];
    __hip_bfloat16* hs = a.hs[j];
    float* als = a.als[j];
    for (int r = 0; r < 20; ++r) {
        int nl = nl0 + r;
        float hv = b2f(hsrc[(size_t)nl * 64 + c]);
        int hb = __float_as_int(hv);
        float a0 = 0.f, a1 = 0.f, a2 = 0.f, a3 = 0.f;
#pragma unroll
        for (int k = 0; k < 64; k += 4) {
            float h0 = __int_as_float(__builtin_amdgcn_readlane(hb, k));
            float h1 = __int_as_float(__builtin_amdgcn_readlane(hb, k + 1));
            float h2 = __int_as_float(__builtin_amdgcn_readlane(hb, k + 2));
            float h3 = __int_as_float(__builtin_amdgcn_readlane(hb, k + 3));
            a0 = fmaf(h0, wreg[k], a0);
            a1 = fmaf(h1, wreg[k + 1], a1);
            a2 = fmaf(h2, wreg[k + 2], a2);
            a3 = fmaf(h3, wreg[k + 3], a3);
        }
        float acc = (a0 + a1) + (a2 + a3);
        hs[(size_t)nl * 64 + c] = f2b(acc);
        float p = acc * ac;
        p += __shfl_xor(p, 8, 16);
        p += __shfl_xor(p, 4, 16);
        p += __shfl_xor(p, 2, 16);
        p += __shfl_xor(p, 1, 16);
        if ((c & 15) == 0) als[(size_t)nl * 4 + (c >> 4)] = p;
    }
}

// ------------------- batched counting sort by dst (5 etypes) ---------------
struct SortArgs {
    const int* ei[5]; int* rowptr[5]; int* cursor[5]; int* cols[5]; int* part[5];
    int n[5];   // Ndst+1
};
__global__ void k_hist5(SortArgs s)
{
    int j = blockIdx.y;
    int e = blockIdx.x * 256 + threadIdx.x;
    if (e >= NE) return;
    atomicAdd(&s.rowptr[j][s.ei[j][NE + e] + 1], 1);
}
__global__ void k_scanb5(SortArgs s)
{
    __shared__ int sh[256];
    int j = blockIdx.y;
    int* a = s.rowptr[j];
    int n = s.n[j];
    int tid = threadIdx.x;
    int i = blockIdx.x * 256 + tid;
    int v = (i < n) ? a[i] : 0;
    sh[tid] = v; __syncthreads();
    for (int off = 1; off < 256; off <<= 1) {
        int t = (tid >= off) ? sh[tid - off] : 0;
        __syncthreads();
        sh[tid] += t;
        __syncthreads();
    }
    if (i < n) a[i] = sh[tid];
    if (tid == 255) s.part[j][blockIdx.x] = sh[255];
}
__global__ void k_scanp5(SortArgs s)
{
    __shared__ int sh[512];
    int j = blockIdx.x;
    int* part = s.part[j];
    int tid = threadIdx.x;
    int v = (tid < 391) ? part[tid] : 0;
    sh[tid] = v; __syncthreads();
    for (int off = 1; off < 512; off <<= 1) {
        int t = (tid >= off) ? sh[tid - off] : 0;
        __syncthreads();
        sh[tid] += t;
        __syncthreads();
    }
    if (tid < 391) part[tid] = sh[tid] - v;    // exclusive
}
__global__ void k_scana5(SortArgs s)
{
    int j = blockIdx.y;
    int i = blockIdx.x * 256 + threadIdx.x;
    if (i < s.n[j]) s.rowptr[j][i] += s.part[j][blockIdx.x];
}
__global__ void k_scatter5(SortArgs s)
{
    int j = blockIdx.y;
    int e = blockIdx.x * 256 + threadIdx.x;
    if (e >= NE) return;
    const int* ei = s.ei[j];
    int src = ei[e], d = ei[NE + e];
    int pos = atomicAdd(&s.cursor[j][d], 1);
    s.cols[j][pos] = src;
}

// ------------------ fused per-dst GAT gather + LN + ReLU -------------------
// w-dedup: lanes 0..31 compute w for (slot u=lane>>2, head=lane&3) once;
// channel-lanes read w via shfl. 1 als-gather + 1 exp per chunk per lane
// (vs 8 + 8 before).
__device__ __forceinline__ float gat_side(int n, int lane, int c, int hh, float hrow,
    const float* We, const int* __restrict__ rp, const int* __restrict__ cols,
    const __hip_bfloat16* __restrict__ hs, const float* __restrict__ als)
{
    float aldv = 0.f;
#pragma unroll
    for (int hp = 0; hp < 4; ++hp) {
        float v = hrow * We[c * 4 + hp];
        v += __shfl_xor(v, 32, 64);
        v += __shfl_xor(v, 16, 64);
        v += __shfl_xor(v, 8, 64);
        v += __shfl_xor(v, 4, 64);
        v += __shfl_xor(v, 2, 64);
        v += __shfl_xor(v, 1, 64);
        if (hh == hp) aldv = v;
    }
    // w-computing lane p handles head h2=p&3; aldv[h2] lives in lane h2*16.
    float aldc = __shfl(aldv, (lane & 3) * 16, 64);
    int us = (lane >> 2) & 7;                 // this lane's w-slot
    float acc = 0.f, den = 0.f;
    int beg = rp[n], end = rp[n + 1];
    for (int e = beg; e < end; e += 8) {
        int idx[8];
#pragma unroll
        for (int u = 0; u < 8; ++u) {
            int ee = e + u;
            idx[u] = cols[(ee < end) ? ee : beg];
        }
        // one w per (slot,head) in lanes 0..31 (32..63 mirror, unused)
        float alv = als[(size_t)idx[us] * 4 + (lane & 3)] + aldc;
        alv = (alv > 0.f) ? alv : 0.2f * alv;      // leaky_relu 0.2
        float wcomp = __expf(fminf(alv, 60.f));
        if (e + us >= end) wcomp = 0.f;            // predicate invalid slots
        float gv[8];
#pragma unroll
        for (int u = 0; u < 8; ++u) gv[u] = b2f(hs[(size_t)idx[u] * 64 + c]);
#pragma unroll
        for (int u = 0; u < 8; ++u) {
            float w = __shfl(wcomp, u * 4 + hh, 64);
            acc = fmaf(w, gv[u], acc);
            den += w;
        }
    }
    return acc / (den + 1e-16f);
}

struct DstArgs {
    __hip_bfloat16* h; int net; int last; int pad;
    const int* rp0; const int* cols0; const __hip_bfloat16* hs0; const float* als0;
    const float* Wd0; const float* ad0; const float* b0;
    const int* rp1; const int* cols1; const __hip_bfloat16* hs1; const float* als1;
    const float* Wd1; const float* ad1; const float* b1;
    const float* g; const float* bb;
    void* out; size_t obase; const int* flag;
};
struct DstAll { DstArgs a[3]; int blkoff[4]; };

__global__ void k_dst(DstAll all)
{
    int bid = blockIdx.x;
    int t = (bid >= all.blkoff[1]) + (bid >= all.blkoff[2]);
    const DstArgs& a = all.a[t];
    __shared__ float We0[256], We1[256];
    int tid = threadIdx.x;
    {
        int k = tid >> 2, h2 = tid & 3;
        float s0 = 0.f;
        for (int cc = 0; cc < 16; ++cc)
            s0 += a.Wd0[k * 64 + h2 * 16 + cc] * a.ad0[h2 * 16 + cc];
        We0[tid] = s0;
        if (a.net > 1) {
            float s1 = 0.f;
            for (int cc = 0; cc < 16; ++cc)
                s1 += a.Wd1[k * 64 + h2 * 16 + cc] * a.ad1[h2 * 16 + cc];
            We1[tid] = s1;
        }
    }
    __syncthreads();
    int wid = tid >> 6, lane = tid & 63, c = lane, hh = c >> 4;
    float b0c = a.b0[c];
    float b1c = (a.net > 1) ? a.b1[c] : 0.f;
    float gc = a.g[c], bbc = a.bb[c];
    int base = (bid - all.blkoff[t]) * 16;    // 16 nodes/block
    for (int r = 0; r < 4; ++r) {
        int n = base + r * 4 + wid;
        size_t i64 = (size_t)n * 64 + c;
        float hrow = b2f(a.h[i64]);
        float x = hrow + b0c + b1c;
        x += gat_side(n, lane, c, hh, hrow, We0, a.rp0, a.cols0, a.hs0, a.als0);
        if (a.net > 1)
            x += gat_side(n, lane, c, hh, hrow, We1, a.rp1, a.cols1, a.hs1, a.als1);
        float s = x;
#pragma unroll
        for (int off = 32; off >= 1; off >>= 1) s += __shfl_xor(s, off, 64);
        float mu = s * (1.f / 64.f);
        float dlt = x - mu;
        float v2 = dlt * dlt;
#pragma unroll
        for (int off = 32; off >= 1; off >>= 1) v2 += __shfl_xor(v2, off, 64);
        float y = dlt * rsqrtf(v2 * (1.f / 64.f) + 1e-5f) * gc + bbc;
        y = fmaxf(y, 0.f);
        if (!a.last) a.h[i64] = f2b(y);
        else {
            if (*a.flag) ((float*)a.out)[a.obase + i64] = y;
            else         ((__hip_bfloat16*)a.out)[a.obase + i64] = f2b(y);
        }
    }
}

extern "C" void kernel_launch(void* const* d_in, const int* in_sizes, int n_in,
                              void* d_out, int out_size, void* d_ws, size_t ws_size,
                              hipStream_t stream)
{
    (void)n_in; (void)out_size; (void)ws_size;
    char* ws = (char*)d_ws;
    int* flag = (int*)ws;
    float* params = (float*)(ws + 256);

    size_t off[17]; off[0] = 0;
    for (int i = 0; i < 16; ++i) off[i + 1] = off[i] + (size_t)in_sizes[i];

    const float* Wi = params + off[3]; const float* bi = params + off[4];
    const float* Wq = params + off[5]; const float* bq = params + off[6];
    const float* Wt = params + off[7]; const float* bt = params + off[8];
    const float* Wsrc = params + off[9];
    const float* Wdst = params + off[10];
    const float* asrc = params + off[11];
    const float* adst = params + off[12];
    const float* cbias = params + off[13];
    const float* lng = params + off[14];
    const float* lnb = params + off[15];

    __hip_bfloat16* h   = (__hip_bfloat16*)(ws + 7600000);
    __hip_bfloat16* h_i = h;
    __hip_bfloat16* h_q = h + (size_t)NI * 64;
    __hip_bfloat16* h_t = h + (size_t)(NI + NQ) * 64;
    __hip_bfloat16* hs_all = (__hip_bfloat16*)(ws + 39600000);
    float* als_all = (float*)(ws + 97200000);
    const size_t rowbase[5] = { 0, 100000, 200000, 300000, 400000 };

    const size_t RPS = 400032;
    SortArgs sa;
    const int Ndst_of[5] = { NI, NQ, NI, NT, NQ };
    for (int j = 0; j < 5; ++j) {
        sa.ei[j]     = (const int*)d_in[16 + j];
        sa.rowptr[j] = (int*)(ws + 104400000 + j * RPS);
        sa.cursor[j] = (int*)(ws + 106400320 + j * RPS);
        sa.cols[j]   = (int*)(ws + 108400480 + (size_t)j * 2000000);
        sa.part[j]   = (int*)(ws + 118400480 + j * 2048);
        sa.n[j]      = Ndst_of[j] + 1;
    }

    // ---- dtype detect + widen PARAM tensors (3..15) only ----
    k_detect<<<1, 256, 0, stream>>>((const unsigned short*)d_in[0], flag);
    ConvArgs ca;
    for (int i = 0; i < 16; ++i) {
        ca.src[i] = d_in[i];
        ca.dst[i] = params + off[i];
        ca.n[i] = (i >= 3) ? in_sizes[i] : 0;
    }
    k_convert<<<dim3(160, 16), 256, 0, stream>>>(ca, flag);

    // ---- input projections ----
    k_inproj<<<(NI + 3) / 4, 256, 0, stream>>>(d_in[0], NI, 8, Wi, bi, h_i, flag);
    k_inproj<<<(NQ + 3) / 4, 256, 0, stream>>>(d_in[1], NQ, 6, Wq, bq, h_q, flag);
    k_inproj<<<(NT + 3) / 4, 256, 0, stream>>>(d_in[2], NT, 8, Wt, bt, h_t, flag);

    // ---- batched counting sort (reused by both layers) ----
    hipMemsetAsync(ws + 104400000, 0, 5 * RPS, stream);
    k_hist5<<<dim3((NE + 255) / 256, 5), 256, 0, stream>>>(sa);
    k_scanb5<<<dim3(391, 5), 256, 0, stream>>>(sa);
    k_scanp5<<<5, 512, 0, stream>>>(sa);
    k_scana5<<<dim3(391, 5), 256, 0, stream>>>(sa);
    hipMemcpyAsync(ws + 106400320, ws + 104400000, 5 * RPS, hipMemcpyDeviceToDevice, stream);
    k_scatter5<<<dim3((NE + 255) / 256, 5), 256, 0, stream>>>(sa);

    const __hip_bfloat16* hsrc_of[5] = { h_i, h_i, h_q, h_q, h_t };

    for (int l = 0; l < 2; ++l) {
        TfArgs ta;
        for (int j = 0; j < 5; ++j) {
            ta.hsrc[j] = hsrc_of[j];
            ta.W[j] = Wsrc + (size_t)(l * 5 + j) * 4096;
            ta.avec[j] = asrc + (l * 5 + j) * 64;
            ta.hs[j] = hs_all + rowbase[j] * 64;
            ta.als[j] = als_all + rowbase[j] * 4;
        }
        k_transform_all<<<450000 / 80, 256, 0, stream>>>(ta);

        int last = (l == 1);
        DstAll da;
        da.blkoff[0] = 0; da.blkoff[1] = NI / 16;
        da.blkoff[2] = NI / 16 + NQ / 16; da.blkoff[3] = NI / 16 + NQ / 16 + NT / 16;
        struct Spec { __hip_bfloat16* hd; int j0, j1, lnidx; size_t obase; };
        Spec sp[3] = {
            { h_i, 0, 2, 0, 0 },
            { h_q, 1, 4, 1, (size_t)NI * 64 },
            { h_t, 3, -1, 2, (size_t)(NI + NQ) * 64 },
        };
        for (int t = 0; t < 3; ++t) {
            DstArgs& dd = da.a[t];
            dd.h = sp[t].hd; dd.net = (sp[t].j1 >= 0) ? 2 : 1; dd.last = last; dd.pad = 0;
            int j0 = sp[t].j0;
            dd.rp0 = sa.rowptr[j0]; dd.cols0 = sa.cols[j0];
            dd.hs0 = hs_all + rowbase[j0] * 64; dd.als0 = als_all + rowbase[j0] * 4;
            dd.Wd0 = Wdst + (size_t)(l * 5 + j0) * 4096;
            dd.ad0 = adst + (l * 5 + j0) * 64;
            dd.b0 = cbias + (size_t)(l * 5 + j0) * 64;
            int jj = (sp[t].j1 >= 0) ? sp[t].j1 : j0;
            dd.rp1 = sa.rowptr[jj]; dd.cols1 = sa.cols[jj];
            dd.hs1 = hs_all + rowbase[jj] * 64; dd.als1 = als_all + rowbase[jj] * 4;
            dd.Wd1 = Wdst + (size_t)(l * 5 + jj) * 4096;
            dd.ad1 = adst + (l * 5 + jj) * 64;
            dd.b1 = cbias + (size_t)(l * 5 + jj) * 64;
            dd.g = lng + (size_t)(l * 3 + sp[t].lnidx) * 64;
            dd.bb = lnb + (size_t)(l * 3 + sp[t].lnidx) * 64;
            dd.out = d_out; dd.obase = sp[t].obase; dd.flag = flag;
        }
        k_dst<<<da.blkoff[3], 256, 0, stream>>>(da);
    }
}